// Round 13
// baseline (390.022 us; speedup 1.0000x reference)
//
#include <hip/hip_runtime.h>

// ---------------------------------------------------------------------------
// Cosine-attention transformer block, MI355X gfx950.  Round 13: 3 blocks/CU.
//
// gemmo2: BM=BN=128, BK=32, 256 thr = 4 waves (2x2, per-wave 64x64).
//   DEPTH=3 rotating buffers, LDS 3 x (A[128][32]+B[128][32]) bf16 = 48 KB
//   -> 3 blocks/CU (12 waves, 3 independent barrier domains).  Single frag
//   set + acc = ~120 VGPR, __launch_bounds__(256,4) caps at 128 (16 waves/CU
//   VGPR-wise; LDS is the 3-block cap).
//   Per K-tile t: stage(t+2)->pS (4 gl_lds, 4KB each); read frags(t)<-pR
//   (8 ds_read_b128, swizzle granule^=((row>>1)&3): aggregate 8 words/bank =
//   conflict-free); 16 MFMA (setprio-wrapped); vmcnt(4) [oldest outstanding
//   4 = tile t+1 -> landed]; s_barrier; rotate (pR,pN,pS)<-(pN,pS,pR).
//   Overwrite safety: barrier-at-iter-end + MFMA reg-dependency => all
//   waves' reads(t) consumed before any wave's stage(t+3) targets pR;
//   gl_lds lands >=180cy after issue on top.  Prologue: stage t0,t1;
//   vmcnt(4) [t0 landed]; barrier.  Tail: t+2>=NT -> no stage; vmcnt(0)
//   while t+1<NT.  NT=K/32 in {32,64,128}.
//
// Streaming change: l2-norm folded into sim epilogue (MODE=3): sim computes
//   Q@K^T on unnormalized bf16 Q,K and scales acc*rq[r]*rk[c] in f32
//   (mathematically identical, one less bf16 rounding).  norms_kernel
//   writes only rq/rk (64 KB) instead of materializing Qn/Kn (32 MB).
// ---------------------------------------------------------------------------

using u16 = unsigned short;
using bf16x8 = __attribute__((ext_vector_type(8))) __bf16;
using f32x4  = __attribute__((ext_vector_type(4))) float;

__device__ __forceinline__ u16 f2bf(float f) {
  unsigned u = __float_as_uint(f);
  unsigned r = (u + 0x7FFFu + ((u >> 16) & 1u)) >> 16;
  return (u16)r;
}
__device__ __forceinline__ float bf2f(u16 h) {
  return __uint_as_float(((unsigned)h) << 16);
}

// XCD-bijective chunking (m204) then supertile (byloc fastest).
__device__ __forceinline__ void decomp(int lid, int nwg, int gx, int gy,
                                       int gby, int& bx, int& by, int& bz) {
  const int q = nwg >> 3, r = nwg & 7;
  const int xcd = lid & 7, jj = lid >> 3;
  const int wg = (xcd < r ? xcd * (q + 1) : r * (q + 1) + (xcd - r) * q) + jj;
  const int byloc = wg % gby;
  const int t1 = wg / gby;
  bx = t1 % gx;
  const int t2 = t1 / gx;
  const int nb = gy / gby;
  const int band = t2 % nb;
  bz = t2 / nb;
  by = band * gby + byloc;
}

// ---------------- fused fp32 -> bf16 cast (7 segments) ----------------
struct CastSegs {
  const float* src[7];
  u16* dst[7];
  long beg[8];
};
__global__ __launch_bounds__(256) void cast_multi_kernel(CastSegs cs) {
  long idx = (long)blockIdx.x * 256 + threadIdx.x;
  if (idx >= cs.beg[7]) return;
  int seg = 0;
#pragma unroll
  for (int s = 1; s < 7; ++s) seg += (idx >= cs.beg[s]) ? 1 : 0;
  const long loc = idx - cs.beg[seg];
  float4 v = reinterpret_cast<const float4*>(cs.src[seg])[loc];
  ushort4 o;
  o.x = f2bf(v.x); o.y = f2bf(v.y); o.z = f2bf(v.z); o.w = f2bf(v.w);
  reinterpret_cast<ushort4*>(cs.dst[seg])[loc] = o;
}

// ------ inverse row norms of Q,K bf16 [8192][1024] -> rq,rk f32[8192] ------
__global__ __launch_bounds__(256) void norms_kernel(
    const u16* __restrict__ Qi, const u16* __restrict__ Ki,
    float* __restrict__ rq, float* __restrict__ rk) {
  __shared__ float red[4];
  long row = blockIdx.x;
  const u16* in;
  float* out;
  if (row < 8192) { in = Qi + row * 1024; out = rq + row; }
  else            { in = Ki + (row - 8192) * 1024; out = rk + (row - 8192); }
  const int tid = threadIdx.x, lane = tid & 63, wave = tid >> 6;
  ushort4 h = *reinterpret_cast<const ushort4*>(in + tid * 4);
  float x0 = bf2f(h.x), x1 = bf2f(h.y), x2 = bf2f(h.z), x3 = bf2f(h.w);
  float ss = x0 * x0 + x1 * x1 + x2 * x2 + x3 * x3;
#pragma unroll
  for (int o = 32; o; o >>= 1) ss += __shfl_xor(ss, o);
  if (lane == 0) red[wave] = ss;
  __syncthreads();
  if (tid == 0) {
    ss = red[0] + red[1] + red[2] + red[3];
    *out = 1.0f / fmaxf(sqrtf(ss), 1e-12f);
  }
}

// ---------------- bf16 transpose ----------------
__global__ void transpose_kernel(const u16* __restrict__ in, u16* __restrict__ out,
                                 int rows, int cols) {
  __shared__ u16 t[32][33];
  const int c0 = blockIdx.x * 32, r0 = blockIdx.y * 32;
  const long off = (long)blockIdx.z * rows * cols;
  const u16* ib = in + off;
  u16* ob = out + off;
  const int tx = threadIdx.x, ty = threadIdx.y;
#pragma unroll
  for (int j = 0; j < 4; ++j)
    t[ty + j * 8][tx] = ib[(long)(r0 + ty + j * 8) * cols + c0 + tx];
  __syncthreads();
#pragma unroll
  for (int j = 0; j < 4; ++j)
    ob[(long)(c0 + ty + j * 8) * rows + r0 + tx] = t[tx][ty + j * 8];
}

// ---------------- row softmax: bf16 [rows][2048] -> bf16 ----------------
__global__ __launch_bounds__(256) void softmax_kernel(
    const u16* __restrict__ in, u16* __restrict__ out) {
  __shared__ float red[4];
  long row = blockIdx.x;
  const int tid = threadIdx.x, lane = tid & 63, wave = tid >> 6;
  const u16* p = in + row * 2048 + tid * 8;
  ushort4 h0 = *reinterpret_cast<const ushort4*>(p);
  ushort4 h1 = *reinterpret_cast<const ushort4*>(p + 4);
  float v[8];
  v[0] = bf2f(h0.x); v[1] = bf2f(h0.y); v[2] = bf2f(h0.z); v[3] = bf2f(h0.w);
  v[4] = bf2f(h1.x); v[5] = bf2f(h1.y); v[6] = bf2f(h1.z); v[7] = bf2f(h1.w);
  float m = v[0];
#pragma unroll
  for (int i = 1; i < 8; ++i) m = fmaxf(m, v[i]);
#pragma unroll
  for (int o = 32; o; o >>= 1) m = fmaxf(m, __shfl_xor(m, o));
  if (lane == 0) red[wave] = m;
  __syncthreads();
  m = fmaxf(fmaxf(red[0], red[1]), fmaxf(red[2], red[3]));
  float s = 0.0f;
#pragma unroll
  for (int i = 0; i < 8; ++i) { v[i] = __expf(v[i] - m); s += v[i]; }
#pragma unroll
  for (int o = 32; o; o >>= 1) s += __shfl_xor(s, o);
  __syncthreads();
  if (lane == 0) red[wave] = s;
  __syncthreads();
  s = red[0] + red[1] + red[2] + red[3];
  float inv = 1.0f / s;
  ushort4 o0, o1;
  o0.x = f2bf(v[0] * inv); o0.y = f2bf(v[1] * inv);
  o0.z = f2bf(v[2] * inv); o0.w = f2bf(v[3] * inv);
  o1.x = f2bf(v[4] * inv); o1.y = f2bf(v[5] * inv);
  o1.z = f2bf(v[6] * inv); o1.w = f2bf(v[7] * inv);
  *reinterpret_cast<ushort4*>(out + row * 2048 + tid * 8) = o0;
  *reinterpret_cast<ushort4*>(out + row * 2048 + tid * 8 + 4) = o1;
}

// ============== gemmo2: lean 1-barrier BK=32, 3 blocks/CU ==============
// C[m,n] = sum_k A[m,k]*B[n,k] (+bias) (+relu).  K%32==0, NT>=4.
// MODE: 0 f32 out, 1 bf16 out, 2 QKV column-route, 3 bf16 with
//       row-scale bias(=rq) and col-scale bias2(=rk) applied in f32.
template <int MODE>
__global__ __launch_bounds__(256, 4) void gemmo2(
    const u16* __restrict__ A, const u16* __restrict__ Bw,
    const float* __restrict__ bias, void* __restrict__ Cout,
    const float* __restrict__ bias2, void* __restrict__ Cout2,
    const float* __restrict__ bias3, void* __restrict__ Cout3,
    int N, int K, long batchA, long batchB, long batchC, int relu,
    int gx, int gy, int gby) {
  constexpr int BUF = 128 * 32;            // u16 per matrix per buffer (8 KB)
  __shared__ u16 lds[3 * 2 * BUF];         // 48 KB -> 3 blocks/CU
  // buffer i: A at lds + i*2*BUF, B at lds + i*2*BUF + BUF

  int bx, by, bz;
  decomp(blockIdx.x, gridDim.x, gx, gy, gby, bx, by, bz);

  const int tid = threadIdx.x, wave = tid >> 6, lane = tid & 63;
  const int wr = wave >> 1, wc = wave & 1;   // 2x2 waves, per-wave 64x64
  const int fr = lane & 15, hi = lane >> 4;  // hi in 0..3 (k-group of 8)

  const long Abase = bz * batchA + (long)by * 128 * K;
  const long Bbase = bz * batchB + (long)bx * 128 * K;

  // ds_read offsets (u16 units): rows of [128][32]; granule^=((row>>1)&3)
  int aoff[4], boff[4];
#pragma unroll
  for (int m = 0; m < 4; ++m) {
    const int row = wr * 64 + m * 16 + fr;
    aoff[m] = row * 32 + ((hi ^ ((row >> 1) & 3)) * 8);
  }
#pragma unroll
  for (int n = 0; n < 4; ++n) {
    const int row = wc * 64 + n * 16 + fr;
    boff[n] = row * 32 + ((hi ^ ((row >> 1) & 3)) * 8);
  }

  // stage sources (pre-swizzled global, m173): 2 calls per matrix, 64 rows ea;
  // dest linear tid*16B -> prow = rr*64 + (tid>>2), phys granule tid&3,
  // logical granule = (tid&3) ^ ((prow>>1)&3) = (tid&3) ^ ((tid>>3)&3).
  const int srow = tid >> 2;
  const int g8 = (((tid & 3) ^ ((tid >> 3) & 3)) * 8);
  long asrc[2], bsrc[2];
#pragma unroll
  for (int rr = 0; rr < 2; ++rr) {
    asrc[rr] = Abase + (long)(rr * 64 + srow) * K + g8;
    bsrc[rr] = Bbase + (long)(rr * 64 + srow) * K + g8;
  }

#define STAGE_TILE(bufp, T)                                                    \
  {                                                                            \
    const int k0_ = (T) << 5;                                                  \
    __builtin_amdgcn_global_load_lds(                                          \
        (const __attribute__((address_space(1))) void*)(A + asrc[0] + k0_),    \
        (__attribute__((address_space(3))) void*)((bufp) + tid * 8), 16, 0, 0);\
    __builtin_amdgcn_global_load_lds(                                          \
        (const __attribute__((address_space(1))) void*)(A + asrc[1] + k0_),    \
        (__attribute__((address_space(3))) void*)((bufp) + 2048 + tid * 8),    \
        16, 0, 0);                                                             \
    __builtin_amdgcn_global_load_lds(                                          \
        (const __attribute__((address_space(1))) void*)(Bw + bsrc[0] + k0_),   \
        (__attribute__((address_space(3))) void*)((bufp) + BUF + tid * 8),     \
        16, 0, 0);                                                             \
    __builtin_amdgcn_global_load_lds(                                          \
        (const __attribute__((address_space(1))) void*)(Bw + bsrc[1] + k0_),   \
        (__attribute__((address_space(3))) void*)((bufp) + BUF + 2048 + tid * 8), \
        16, 0, 0);                                                             \
  }

  const int NT = K >> 5;  // 32 / 64 / 128 for our shapes

  u16* pR = lds;               // read buffer (tile t)
  u16* pN = lds + 2 * BUF;     // next (tile t+1)
  u16* pS = lds + 4 * BUF;     // stage target (tile t+2)

  // prologue: stage t0,t1; t0 landed; barrier
  STAGE_TILE(pR, 0)
  STAGE_TILE(pN, 1)
  asm volatile("s_waitcnt vmcnt(4)" ::: "memory");  // t0 landed
  __builtin_amdgcn_s_barrier();

  f32x4 acc[4][4] = {};

  for (int t = 0; t < NT; ++t) {
    const bool st = (t + 2) < NT;
    if (st) STAGE_TILE(pS, t + 2)
    // read frags(t) from pR; compiler emits fine-grained lgkmcnt before MFMA
    bf16x8 a[4], b[4];
#pragma unroll
    for (int m = 0; m < 4; ++m)
      a[m] = *reinterpret_cast<const bf16x8*>(&pR[aoff[m]]);
#pragma unroll
    for (int n = 0; n < 4; ++n)
      b[n] = *reinterpret_cast<const bf16x8*>(&pR[BUF + boff[n]]);
    __builtin_amdgcn_s_setprio(1);
#pragma unroll
    for (int m = 0; m < 4; ++m)
#pragma unroll
      for (int n = 0; n < 4; ++n)
        acc[m][n] = __builtin_amdgcn_mfma_f32_16x16x32_bf16(
            a[m], b[n], acc[m][n], 0, 0, 0);
    __builtin_amdgcn_s_setprio(0);
    if (st) asm volatile("s_waitcnt vmcnt(4)" ::: "memory");   // t+1 landed
    else if (t + 1 < NT) asm volatile("s_waitcnt vmcnt(0)" ::: "memory");
    __builtin_amdgcn_s_barrier();
    u16* tmp = pR; pR = pN; pN = pS; pS = tmp;
  }
#undef STAGE_TILE

  // ---- epilogue ----
  const long cbase = bz * batchC;
  const int crow = by * 128;
  int ccol = bx * 128;
  const float* bp = bias;
  void* cp = Cout;
  constexpr bool obf = (MODE != 0);
  int Nst = N;
  if constexpr (MODE == 2) {
    const int sel = ccol >> 10;  // block-uniform (128-col tiles)
    if (sel == 1) { bp = bias2; cp = Cout2; }
    else if (sel == 2) { bp = bias3; cp = Cout3; }
    ccol &= 1023;
    Nst = 1024;
  }
#pragma unroll
  for (int m = 0; m < 4; ++m) {
    const int r0 = crow + wr * 64 + m * 16 + hi * 4;
#pragma unroll
    for (int n = 0; n < 4; ++n) {
      const int c = ccol + wc * 64 + n * 16 + fr;
      float bb = 0.0f, cscale = 1.0f;
      if constexpr (MODE == 3) { cscale = bias2[bz * 2048 + c]; }
      else { bb = bp ? bp[c] : 0.0f; }
#pragma unroll
      for (int j = 0; j < 4; ++j) {
        float v;
        if constexpr (MODE == 3)
          v = acc[m][n][j] * bias[bz * 2048 + r0 + j] * cscale;
        else {
          v = acc[m][n][j] + bb;
          if (relu) v = fmaxf(v, 0.0f);
        }
        const long idx = cbase + (long)(r0 + j) * Nst + c;
        if (obf) ((u16*)cp)[idx] = f2bf(v);
        else     ((float*)cp)[idx] = v;
      }
    }
  }
}

// ---------------------------------------------------------------------------
extern "C" void kernel_launch(void* const* d_in, const int* in_sizes, int n_in,
                              void* d_out, int out_size, void* d_ws, size_t ws_size,
                              hipStream_t stream) {
  (void)in_sizes; (void)n_in; (void)out_size; (void)ws_size;
  const float* x  = (const float*)d_in[0];
  const float* Wq = (const float*)d_in[1];
  const float* bq = (const float*)d_in[2];
  const float* Wk = (const float*)d_in[3];
  const float* bk = (const float*)d_in[4];
  const float* Wv = (const float*)d_in[5];
  const float* bv = (const float*)d_in[6];
  const float* W1 = (const float*)d_in[7];
  const float* b1 = (const float*)d_in[8];
  const float* W2 = (const float*)d_in[9];
  const float* b2 = (const float*)d_in[10];
  const float* W3 = (const float*)d_in[11];
  const float* b3 = (const float*)d_in[12];

  char* ws = (char*)d_ws;
  const size_t MB = 1u << 20;
  // region 0 [0,64MB): Qbf[0,16) Kbf[16,32) rq/rk[32,32.07)  -> h2 later
  u16* Qbf = (u16*)(ws + 0);
  u16* Kbf = Qbf + 8388608;
  float* rq = (float*)(ws + 32 * MB);
  float* rk = rq + 8192;
  u16* h2  = (u16*)(ws + 0);
  // region 1 [64,96MB): xbf[64,80) Vbf[80,96)  -> P[64,96) after transpose
  u16* xbf = (u16*)(ws + 64 * MB);
  u16* Vbf = xbf + (size_t)8192 * 1024;
  u16* P   = (u16*)(ws + 64 * MB);
  // region 2 [96,120MB): weights bf16
  u16* Wq_b = (u16*)(ws + 96 * MB);
  u16* Wk_b = Wq_b + 1048576;
  u16* Wv_b = Wk_b + 1048576;
  u16* W1_b = Wv_b + 1048576;
  u16* W2_b = W1_b + 1048576;
  u16* W3_b = W2_b + 4194304;
  // region 3 [120,168MB): attnout[120,136) h1[136,152) Vt[152,168)
  u16* attnout = (u16*)(ws + 120 * MB);
  u16* h1      = attnout + 8388608;
  u16* Vt      = h1 + 8388608;

  CastSegs cs;
  cs.src[0] = x;  cs.dst[0] = xbf;
  cs.src[1] = Wq; cs.dst[1] = Wq_b;
  cs.src[2] = Wk; cs.dst[2] = Wk_b;
  cs.src[3] = Wv; cs.dst[3] = Wv_b;
  cs.src[4] = W1; cs.dst[4] = W1_b;
  cs.src[5] = W2; cs.dst[5] = W2_b;
  cs.src[6] = W3; cs.dst[6] = W3_b;
  long szs[7] = {2097152, 262144, 262144, 262144, 262144, 1048576, 1048576};
  long acc0 = 0;
  for (int i = 0; i < 7; ++i) { cs.beg[i] = acc0; acc0 += szs[i]; }
  cs.beg[7] = acc0;
  cast_multi_kernel<<<dim3((unsigned)((acc0 + 255) / 256)), 256, 0, stream>>>(cs);

  dim3 blk(256);
  // 2. fused QKV: M=8192, N=3072, K=1024 (grid 24x64=1536, GBY=8)
  gemmo2<2><<<dim3(24 * 64), blk, 0, stream>>>(
      xbf, Wq_b, bq, Qbf, bk, Kbf, bv, Vbf, 3072, 1024, 0, 0, 0, 0, 24, 64, 8);
  // 3. inverse norms (tiny) + V transpose
  norms_kernel<<<16384, 256, 0, stream>>>(Qbf, Kbf, rq, rk);
  transpose_kernel<<<dim3(32, 64, 4), dim3(32, 8), 0, stream>>>(Vbf, Vt, 2048, 1024);
  // 4. sim = (Q@K^T) * rq[r] * rk[c] -> bf16 P-logits (grid 16x16x4=1024)
  gemmo2<3><<<dim3(16 * 16 * 4), blk, 0, stream>>>(
      Qbf, Kbf, rq, P, rk, nullptr, nullptr, nullptr,
      2048, 1024, 2097152L, 2097152L, 4194304L, 0, 16, 16, 8);
  // 5. softmax (bf16 in/out), in-place on P
  softmax_kernel<<<8192, 256, 0, stream>>>(P, P);
  // 6. attnout = P @ V (grid 8x16x4=512)
  gemmo2<1><<<dim3(8 * 16 * 4), blk, 0, stream>>>(
      P, Vt, nullptr, attnout, nullptr, nullptr, nullptr, nullptr,
      1024, 2048, 4194304L, 2097152L, 2097152L, 0, 8, 16, 8);
  // 7. MLP
  gemmo2<1><<<dim3(8 * 64), blk, 0, stream>>>(
      attnout, W1_b, b1, h1, nullptr, nullptr, nullptr, nullptr,
      1024, 1024, 0, 0, 0, 1, 8, 64, 16);
  gemmo2<1><<<dim3(32 * 64), blk, 0, stream>>>(
      h1, W2_b, b2, h2, nullptr, nullptr, nullptr, nullptr,
      4096, 1024, 0, 0, 0, 1, 32, 64, 8);
  gemmo2<0><<<dim3(8 * 64), blk, 0, stream>>>(
      h2, W3_b, b3, (float*)d_out, nullptr, nullptr, nullptr, nullptr,
      1024, 4096, 0, 0, 0, 0, 8, 64, 16);
}

// Round 14
// 360.133 us; speedup vs baseline: 1.0830x; 1.0830x over previous
//
#include <hip/hip_runtime.h>

// ---------------------------------------------------------------------------
// Cosine-attention transformer block, MI355X gfx950.  Round 14: consolidation.
//
// = R11's GEMM structure (best measured class) + R13's norm-scale fusion
//   (independently validated: identical absmax in R13).
// - gemm256: 256x256 8-phase, BK=64, DEPTH=2, 128 KB LDS, counted vmcnt(8),
//   frag-once snake phases, XOR swizzle granule^=row&7, supertiled
//   XCD-bijective decomp.  Used for QKV (MODE=2), sim (MODE=3: scale by
//   rq[row]*rk[col] in f32), MLP2 (MODE=1).
// - gemmra: RA1 128x256, BK=64, DEPTH=2, 96 KB LDS, vmcnt(6), register
//   read-ahead pipeline.  Used for PV, MLP1, MLP3.
// - norms_kernel: rq/rk = 1/max(||row||,eps) only (64 KB out) — replaces
//   materializing Qn/Kn (saves ~32 MB of writes + 32 MB of sim reads).
//
// Evidence note: all structural GEMM variants (R2-R13) land at 33-35% of
// peak = ~850 TF at K<=2048, matching the guide's verified plain-HIP
// template at the same K (m248: 848 TF @ K=1024).
// ---------------------------------------------------------------------------

using u16 = unsigned short;
using bf16x8 = __attribute__((ext_vector_type(8))) __bf16;
using f32x4  = __attribute__((ext_vector_type(4))) float;

__device__ __forceinline__ u16 f2bf(float f) {
  unsigned u = __float_as_uint(f);
  unsigned r = (u + 0x7FFFu + ((u >> 16) & 1u)) >> 16;
  return (u16)r;
}
__device__ __forceinline__ float bf2f(u16 h) {
  return __uint_as_float(((unsigned)h) << 16);
}

// XCD-bijective chunking (m204) then supertile (byloc fastest).
__device__ __forceinline__ void decomp(int lid, int nwg, int gx, int gy,
                                       int gby, int& bx, int& by, int& bz) {
  const int q = nwg >> 3, r = nwg & 7;
  const int xcd = lid & 7, jj = lid >> 3;
  const int wg = (xcd < r ? xcd * (q + 1) : r * (q + 1) + (xcd - r) * q) + jj;
  const int byloc = wg % gby;
  const int t1 = wg / gby;
  bx = t1 % gx;
  const int t2 = t1 / gx;
  const int nb = gy / gby;
  const int band = t2 % nb;
  bz = t2 / nb;
  by = band * gby + byloc;
}

// ---------------- fused fp32 -> bf16 cast (7 segments) ----------------
struct CastSegs {
  const float* src[7];
  u16* dst[7];
  long beg[8];
};
__global__ __launch_bounds__(256) void cast_multi_kernel(CastSegs cs) {
  long idx = (long)blockIdx.x * 256 + threadIdx.x;
  if (idx >= cs.beg[7]) return;
  int seg = 0;
#pragma unroll
  for (int s = 1; s < 7; ++s) seg += (idx >= cs.beg[s]) ? 1 : 0;
  const long loc = idx - cs.beg[seg];
  float4 v = reinterpret_cast<const float4*>(cs.src[seg])[loc];
  ushort4 o;
  o.x = f2bf(v.x); o.y = f2bf(v.y); o.z = f2bf(v.z); o.w = f2bf(v.w);
  reinterpret_cast<ushort4*>(cs.dst[seg])[loc] = o;
}

// ------ inverse row norms of Q,K bf16 [8192][1024] -> rq,rk f32[8192] ------
__global__ __launch_bounds__(256) void norms_kernel(
    const u16* __restrict__ Qi, const u16* __restrict__ Ki,
    float* __restrict__ rq, float* __restrict__ rk) {
  __shared__ float red[4];
  long row = blockIdx.x;
  const u16* in;
  float* out;
  if (row < 8192) { in = Qi + row * 1024; out = rq + row; }
  else            { in = Ki + (row - 8192) * 1024; out = rk + (row - 8192); }
  const int tid = threadIdx.x, lane = tid & 63, wave = tid >> 6;
  ushort4 h = *reinterpret_cast<const ushort4*>(in + tid * 4);
  float x0 = bf2f(h.x), x1 = bf2f(h.y), x2 = bf2f(h.z), x3 = bf2f(h.w);
  float ss = x0 * x0 + x1 * x1 + x2 * x2 + x3 * x3;
#pragma unroll
  for (int o = 32; o; o >>= 1) ss += __shfl_xor(ss, o);
  if (lane == 0) red[wave] = ss;
  __syncthreads();
  if (tid == 0) {
    ss = red[0] + red[1] + red[2] + red[3];
    *out = 1.0f / fmaxf(sqrtf(ss), 1e-12f);
  }
}

// ---------------- bf16 transpose ----------------
__global__ void transpose_kernel(const u16* __restrict__ in, u16* __restrict__ out,
                                 int rows, int cols) {
  __shared__ u16 t[32][33];
  const int c0 = blockIdx.x * 32, r0 = blockIdx.y * 32;
  const long off = (long)blockIdx.z * rows * cols;
  const u16* ib = in + off;
  u16* ob = out + off;
  const int tx = threadIdx.x, ty = threadIdx.y;
#pragma unroll
  for (int j = 0; j < 4; ++j)
    t[ty + j * 8][tx] = ib[(long)(r0 + ty + j * 8) * cols + c0 + tx];
  __syncthreads();
#pragma unroll
  for (int j = 0; j < 4; ++j)
    ob[(long)(c0 + ty + j * 8) * rows + r0 + tx] = t[tx][ty + j * 8];
}

// ---------------- row softmax: bf16 [rows][2048] -> bf16 ----------------
__global__ __launch_bounds__(256) void softmax_kernel(
    const u16* __restrict__ in, u16* __restrict__ out) {
  __shared__ float red[4];
  long row = blockIdx.x;
  const int tid = threadIdx.x, lane = tid & 63, wave = tid >> 6;
  const u16* p = in + row * 2048 + tid * 8;
  ushort4 h0 = *reinterpret_cast<const ushort4*>(p);
  ushort4 h1 = *reinterpret_cast<const ushort4*>(p + 4);
  float v[8];
  v[0] = bf2f(h0.x); v[1] = bf2f(h0.y); v[2] = bf2f(h0.z); v[3] = bf2f(h0.w);
  v[4] = bf2f(h1.x); v[5] = bf2f(h1.y); v[6] = bf2f(h1.z); v[7] = bf2f(h1.w);
  float m = v[0];
#pragma unroll
  for (int i = 1; i < 8; ++i) m = fmaxf(m, v[i]);
#pragma unroll
  for (int o = 32; o; o >>= 1) m = fmaxf(m, __shfl_xor(m, o));
  if (lane == 0) red[wave] = m;
  __syncthreads();
  m = fmaxf(fmaxf(red[0], red[1]), fmaxf(red[2], red[3]));
  float s = 0.0f;
#pragma unroll
  for (int i = 0; i < 8; ++i) { v[i] = __expf(v[i] - m); s += v[i]; }
#pragma unroll
  for (int o = 32; o; o >>= 1) s += __shfl_xor(s, o);
  __syncthreads();
  if (lane == 0) red[wave] = s;
  __syncthreads();
  s = red[0] + red[1] + red[2] + red[3];
  float inv = 1.0f / s;
  ushort4 o0, o1;
  o0.x = f2bf(v[0] * inv); o0.y = f2bf(v[1] * inv);
  o0.z = f2bf(v[2] * inv); o0.w = f2bf(v[3] * inv);
  o1.x = f2bf(v[4] * inv); o1.y = f2bf(v[5] * inv);
  o1.z = f2bf(v[6] * inv); o1.w = f2bf(v[7] * inv);
  *reinterpret_cast<ushort4*>(out + row * 2048 + tid * 8) = o0;
  *reinterpret_cast<ushort4*>(out + row * 2048 + tid * 8 + 4) = o1;
}

// ======================= gemm256: 256x256 8-phase =========================
// MODE: 0 f32 out, 1 bf16 out, 2 QKV column-route, 3 bf16 cosine-scale
//       (v = acc * bias[bz*2048+row] * bias2[bz*2048+col]).
template <int MODE>
__global__ __launch_bounds__(512, 2) void gemm256(
    const u16* __restrict__ A, const u16* __restrict__ Bw,
    const float* __restrict__ bias, void* __restrict__ Cout,
    const float* __restrict__ bias2, void* __restrict__ Cout2,
    const float* __restrict__ bias3, void* __restrict__ Cout3,
    int N, int K, long batchA, long batchB, long batchC, int relu,
    int gx, int gy, int gby) {
  constexpr int ASZ = 256 * 64;
  constexpr int BSZ = 256 * 64;
  __shared__ u16 lds[2 * (ASZ + BSZ)];  // 128 KB
  u16* const ldsA = lds;
  u16* const ldsB = lds + 2 * ASZ;

  int bx, by, bz;
  decomp(blockIdx.x, gridDim.x, gx, gy, gby, bx, by, bz);

  const int tid = threadIdx.x, wave = tid >> 6, lane = tid & 63;
  const int wr = wave >> 2, wc = wave & 3;
  const int fr = lane & 15, hi = lane >> 4;

  const long Abase = bz * batchA + (long)by * 256 * K;
  const long Bbase = bz * batchB + (long)bx * 256 * K;

  int aoff[2][4][2], boff[2][2][2];
#pragma unroll
  for (int qm = 0; qm < 2; ++qm)
#pragma unroll
    for (int ml = 0; ml < 4; ++ml) {
      const int row = qm * 128 + wr * 64 + ml * 16 + fr;
#pragma unroll
      for (int ks = 0; ks < 2; ++ks)
        aoff[qm][ml][ks] = row * 64 + (((ks * 4 + hi) ^ (row & 7)) * 8);
    }
#pragma unroll
  for (int qn = 0; qn < 2; ++qn)
#pragma unroll
    for (int nl = 0; nl < 2; ++nl) {
      const int row = qn * 128 + wc * 32 + nl * 16 + fr;
#pragma unroll
      for (int ks = 0; ks < 2; ++ks)
        boff[qn][nl][ks] = row * 64 + (((ks * 4 + hi) ^ (row & 7)) * 8);
    }

  const int rA = wave * 8 + (lane >> 3);
  const int g8 = (((lane & 7) ^ (lane >> 3)) * 8);
  long asrc[4], bsrc[4];
#pragma unroll
  for (int rr = 0; rr < 4; ++rr) {
    asrc[rr] = Abase + (long)(rr * 64 + rA) * K + g8;
    bsrc[rr] = Bbase + (long)(rr * 64 + rA) * K + g8;
  }

#define STAGE_A(bufp, rr, k0)                                                  \
  __builtin_amdgcn_global_load_lds(                                            \
      (const __attribute__((address_space(1))) void*)(A + asrc[rr] + (k0)),    \
      (__attribute__((address_space(3))) void*)((bufp) + (rr) * 4096 + wave * 512), \
      16, 0, 0)
#define STAGE_B(bufp, rr, k0)                                                  \
  __builtin_amdgcn_global_load_lds(                                            \
      (const __attribute__((address_space(1))) void*)(Bw + bsrc[rr] + (k0)),   \
      (__attribute__((address_space(3))) void*)((bufp) + (rr) * 4096 + wave * 512), \
      16, 0, 0)
#define MFMA_Q(ah, bh, qm, qn)                                                 \
  __builtin_amdgcn_s_setprio(1);                                               \
  _Pragma("unroll") for (int ks = 0; ks < 2; ++ks)                             \
  _Pragma("unroll") for (int ml = 0; ml < 4; ++ml)                             \
  _Pragma("unroll") for (int nl = 0; nl < 2; ++nl)                             \
    acc[(qm) * 4 + ml][(qn) * 2 + nl] =                                        \
        __builtin_amdgcn_mfma_f32_16x16x32_bf16(                               \
            ah[ml][ks], bh[nl][ks], acc[(qm) * 4 + ml][(qn) * 2 + nl], 0, 0, 0); \
  __builtin_amdgcn_s_setprio(0);

  const int NT = K >> 6;

#pragma unroll
  for (int rr = 0; rr < 4; ++rr) { STAGE_A(ldsA, rr, 0); }
#pragma unroll
  for (int rr = 0; rr < 4; ++rr) { STAGE_B(ldsB, rr, 0); }
#pragma unroll
  for (int rr = 0; rr < 4; ++rr) { STAGE_A(ldsA + ASZ, rr, 64); }
#pragma unroll
  for (int rr = 0; rr < 4; ++rr) { STAGE_B(ldsB + BSZ, rr, 64); }
  asm volatile("s_waitcnt vmcnt(8)" ::: "memory");
  __builtin_amdgcn_s_barrier();

  f32x4 acc[8][4] = {};

  for (int t = 0; t < NT; ++t) {
    u16* const cA = ldsA + (t & 1) * ASZ;
    u16* const cB = ldsB + (t & 1) * BSZ;
    const bool st = (t + 2) < NT;
    const int k2 = (t + 2) << 6;
    bf16x8 a0[4][2], a1[4][2], b0[2][2], b1[2][2];

    // P0: read a0,b0 ; MFMA q00   (compiler emits fine-grained lgkmcnt)
#pragma unroll
    for (int ml = 0; ml < 4; ++ml)
#pragma unroll
      for (int ks = 0; ks < 2; ++ks)
        a0[ml][ks] = *reinterpret_cast<const bf16x8*>(&cA[aoff[0][ml][ks]]);
#pragma unroll
    for (int nl = 0; nl < 2; ++nl)
#pragma unroll
      for (int ks = 0; ks < 2; ++ks)
        b0[nl][ks] = *reinterpret_cast<const bf16x8*>(&cB[boff[0][nl][ks]]);
    __builtin_amdgcn_s_barrier();
    MFMA_Q(a0, b0, 0, 0)
    __builtin_amdgcn_s_barrier();

    // P1: read b1 ; stage Ah0(t+2) ; MFMA q01
#pragma unroll
    for (int nl = 0; nl < 2; ++nl)
#pragma unroll
      for (int ks = 0; ks < 2; ++ks)
        b1[nl][ks] = *reinterpret_cast<const bf16x8*>(&cB[boff[1][nl][ks]]);
    if (st) { STAGE_A(cA, 0, k2); STAGE_A(cA, 1, k2); }
    __builtin_amdgcn_s_barrier();
    MFMA_Q(a0, b1, 0, 1)
    __builtin_amdgcn_s_barrier();

    // P2: read a1 ; stage Bh0(t+2) ; MFMA q11
#pragma unroll
    for (int ml = 0; ml < 4; ++ml)
#pragma unroll
      for (int ks = 0; ks < 2; ++ks)
        a1[ml][ks] = *reinterpret_cast<const bf16x8*>(&cA[aoff[1][ml][ks]]);
    if (st) { STAGE_B(cB, 0, k2); STAGE_B(cB, 1, k2); }
    __builtin_amdgcn_s_barrier();
    MFMA_Q(a1, b1, 1, 1)
    __builtin_amdgcn_s_barrier();

    // P3: stage Ah1,Bh1(t+2) ; MFMA q10 ; vmcnt
    if (st) {
      STAGE_A(cA, 2, k2); STAGE_A(cA, 3, k2);
      STAGE_B(cB, 2, k2); STAGE_B(cB, 3, k2);
    }
    MFMA_Q(a1, b0, 1, 0)
    if (st) asm volatile("s_waitcnt vmcnt(8)" ::: "memory");
    else    asm volatile("s_waitcnt vmcnt(0)" ::: "memory");
    __builtin_amdgcn_s_barrier();
  }
#undef STAGE_A
#undef STAGE_B
#undef MFMA_Q

  const long cbase = bz * batchC;
  const int crow = by * 256;
  int ccol = bx * 256;
  const float* bp = bias;
  void* cp = Cout;
  constexpr bool obf = (MODE != 0);
  int Nst = N;
  if constexpr (MODE == 2) {
    const int sel = ccol >> 10;
    if (sel == 1) { bp = bias2; cp = Cout2; }
    else if (sel == 2) { bp = bias3; cp = Cout3; }
    ccol &= 1023;
    Nst = 1024;
  }
#pragma unroll
  for (int qm = 0; qm < 2; ++qm)
#pragma unroll
    for (int ml = 0; ml < 4; ++ml) {
      const int r0 = crow + qm * 128 + wr * 64 + ml * 16 + hi * 4;
#pragma unroll
      for (int qn = 0; qn < 2; ++qn)
#pragma unroll
        for (int nl = 0; nl < 2; ++nl) {
          const int c = ccol + qn * 128 + wc * 32 + nl * 16 + fr;
          float bb = 0.0f, cscale = 1.0f;
          if constexpr (MODE == 3) { cscale = bias2[bz * 2048 + c]; }
          else { bb = bp ? bp[c] : 0.0f; }
#pragma unroll
          for (int j = 0; j < 4; ++j) {
            float v;
            if constexpr (MODE == 3)
              v = acc[qm * 4 + ml][qn * 2 + nl][j] * bias[bz * 2048 + r0 + j] * cscale;
            else {
              v = acc[qm * 4 + ml][qn * 2 + nl][j] + bb;
              if (relu) v = fmaxf(v, 0.0f);
            }
            const long idx = cbase + (long)(r0 + j) * Nst + c;
            if (obf) ((u16*)cp)[idx] = f2bf(v);
            else     ((float*)cp)[idx] = v;
          }
        }
    }
}

// ======================= gemmra: RA1 128x256 ===============
struct Frags { bf16x8 a[4][2]; bf16x8 b[4][2]; };

template <int MODE>
__global__ __launch_bounds__(512, 2) void gemmra(
    const u16* __restrict__ A, const u16* __restrict__ Bw,
    const float* __restrict__ bias, void* __restrict__ Cout,
    int N, int K, long batchA, long batchB, long batchC, int relu,
    int gx, int gy, int gby) {
  constexpr int ASZ = 128 * 64;
  constexpr int BSZ = 256 * 64;
  __shared__ u16 lds[2 * (ASZ + BSZ)];  // 96 KB
  u16* const ldsA = lds;
  u16* const ldsB = lds + 2 * ASZ;

  int bx, by, bz;
  decomp(blockIdx.x, gridDim.x, gx, gy, gby, bx, by, bz);

  const int tid = threadIdx.x, wave = tid >> 6, lane = tid & 63;
  const int wr = wave >> 2, wc = wave & 3;
  const int fr = lane & 15, hi = lane >> 4;

  const long Abase = bz * batchA + (long)by * 128 * K;
  const long Bbase = bz * batchB + (long)bx * 256 * K;

  int aoff[4][2], boff[4][2];
#pragma unroll
  for (int m = 0; m < 4; ++m) {
    const int qm = m >> 1, ml = m & 1;
    const int row = qm * 64 + wr * 32 + ml * 16 + fr;
#pragma unroll
    for (int ks = 0; ks < 2; ++ks)
      aoff[m][ks] = row * 64 + (((ks * 4 + hi) ^ (row & 7)) * 8);
  }
#pragma unroll
  for (int n = 0; n < 4; ++n) {
    const int qn = n >> 1, nl = n & 1;
    const int row = qn * 128 + wc * 32 + nl * 16 + fr;
#pragma unroll
    for (int ks = 0; ks < 2; ++ks)
      boff[n][ks] = row * 64 + (((ks * 4 + hi) ^ (row & 7)) * 8);
  }

  const int rA = wave * 8 + (lane >> 3);
  const int g8 = (((lane & 7) ^ (lane >> 3)) * 8);
  long asrc[2], bsrc[4];
#pragma unroll
  for (int rr = 0; rr < 2; ++rr) asrc[rr] = Abase + (long)(rr * 64 + rA) * K + g8;
#pragma unroll
  for (int rr = 0; rr < 4; ++rr) bsrc[rr] = Bbase + (long)(rr * 64 + rA) * K + g8;

#define STAGE_A(bufp, rr, k0)                                                  \
  __builtin_amdgcn_global_load_lds(                                            \
      (const __attribute__((address_space(1))) void*)(A + asrc[rr] + (k0)),    \
      (__attribute__((address_space(3))) void*)((bufp) + (rr) * 4096 + wave * 512), \
      16, 0, 0)
#define STAGE_B(bufp, rr, k0)                                                  \
  __builtin_amdgcn_global_load_lds(                                            \
      (const __attribute__((address_space(1))) void*)(Bw + bsrc[rr] + (k0)),   \
      (__attribute__((address_space(3))) void*)((bufp) + (rr) * 4096 + wave * 512), \
      16, 0, 0)
#define STAGE_TILE(T)                                                          \
  {                                                                            \
    u16* sA_ = ldsA + ((T) & 1) * ASZ;                                         \
    u16* sB_ = ldsB + ((T) & 1) * BSZ;                                         \
    const int k0_ = (T) << 6;                                                  \
    STAGE_A(sA_, 0, k0_); STAGE_A(sA_, 1, k0_);                                \
    STAGE_B(sB_, 0, k0_); STAGE_B(sB_, 1, k0_);                                \
    STAGE_B(sB_, 2, k0_); STAGE_B(sB_, 3, k0_);                                \
  }
#define READ_FRAGS(F, T)                                                       \
  {                                                                            \
    u16* rA_ = ldsA + ((T) & 1) * ASZ;                                         \
    u16* rB_ = ldsB + ((T) & 1) * BSZ;                                         \
    _Pragma("unroll") for (int m = 0; m < 4; ++m)                              \
    _Pragma("unroll") for (int ks = 0; ks < 2; ++ks)                           \
      F.a[m][ks] = *reinterpret_cast<const bf16x8*>(&rA_[aoff[m][ks]]);        \
    _Pragma("unroll") for (int n = 0; n < 4; ++n)                              \
    _Pragma("unroll") for (int ks = 0; ks < 2; ++ks)                           \
      F.b[n][ks] = *reinterpret_cast<const bf16x8*>(&rB_[boff[n][ks]]);        \
  }
#define RA_ITER(T, FC, FN)                                                     \
  {                                                                            \
    if ((T) + 2 < NT) STAGE_TILE((T) + 2)                                      \
    if ((T) + 1 < NT) {                                                        \
      if ((T) + 2 < NT) asm volatile("s_waitcnt vmcnt(6)" ::: "memory");       \
      else              asm volatile("s_waitcnt vmcnt(0)" ::: "memory");       \
      __builtin_amdgcn_s_barrier();                                            \
      READ_FRAGS(FN, (T) + 1)                                                  \
      __builtin_amdgcn_s_barrier();                                            \
    }                                                                          \
    __builtin_amdgcn_s_setprio(1);                                             \
    _Pragma("unroll") for (int ks = 0; ks < 2; ++ks)                           \
    _Pragma("unroll") for (int m = 0; m < 4; ++m)                              \
    _Pragma("unroll") for (int n = 0; n < 4; ++n)                              \
      acc[m][n] = __builtin_amdgcn_mfma_f32_16x16x32_bf16(                     \
          FC.a[m][ks], FC.b[n][ks], acc[m][n], 0, 0, 0);                       \
    __builtin_amdgcn_s_setprio(0);                                             \
  }

  const int NT = K >> 6;

  f32x4 acc[4][4] = {};
  Frags fA, fB;

  STAGE_TILE(0)
  STAGE_TILE(1)
  asm volatile("s_waitcnt vmcnt(6)" ::: "memory");
  __builtin_amdgcn_s_barrier();
  READ_FRAGS(fA, 0)
  asm volatile("s_waitcnt lgkmcnt(0)" ::: "memory");
  __builtin_amdgcn_sched_barrier(0);
  __builtin_amdgcn_s_barrier();

  for (int t = 0; t < NT; t += 2) {
    RA_ITER(t, fA, fB)
    RA_ITER(t + 1, fB, fA)
  }
#undef STAGE_A
#undef STAGE_B
#undef STAGE_TILE
#undef READ_FRAGS
#undef RA_ITER

  const long cbase = bz * batchC;
  const int crow = by * 128;
  const int ccol = bx * 256;
  constexpr bool obf = (MODE == 1);
#pragma unroll
  for (int m = 0; m < 4; ++m) {
    const int qm = m >> 1, ml = m & 1;
    const int r0 = crow + qm * 64 + wr * 32 + ml * 16 + hi * 4;
#pragma unroll
    for (int n = 0; n < 4; ++n) {
      const int qn = n >> 1, nl = n & 1;
      const int c = ccol + qn * 128 + wc * 32 + nl * 16 + fr;
      const float bb = bias ? bias[c] : 0.0f;
#pragma unroll
      for (int j = 0; j < 4; ++j) {
        float v = acc[m][n][j] + bb;
        if (relu) v = fmaxf(v, 0.0f);
        const long idx = cbase + (long)(r0 + j) * N + c;
        if (obf) ((u16*)Cout)[idx] = f2bf(v);
        else     ((float*)Cout)[idx] = v;
      }
    }
  }
}

// ---------------------------------------------------------------------------
extern "C" void kernel_launch(void* const* d_in, const int* in_sizes, int n_in,
                              void* d_out, int out_size, void* d_ws, size_t ws_size,
                              hipStream_t stream) {
  (void)in_sizes; (void)n_in; (void)out_size; (void)ws_size;
  const float* x  = (const float*)d_in[0];
  const float* Wq = (const float*)d_in[1];
  const float* bq = (const float*)d_in[2];
  const float* Wk = (const float*)d_in[3];
  const float* bk = (const float*)d_in[4];
  const float* Wv = (const float*)d_in[5];
  const float* bv = (const float*)d_in[6];
  const float* W1 = (const float*)d_in[7];
  const float* b1 = (const float*)d_in[8];
  const float* W2 = (const float*)d_in[9];
  const float* b2 = (const float*)d_in[10];
  const float* W3 = (const float*)d_in[11];
  const float* b3 = (const float*)d_in[12];

  char* ws = (char*)d_ws;
  const size_t MB = 1u << 20;
  // region 0 [0,64MB): Qbf[0,16) Kbf[16,32) rq/rk[32,~32.07)  -> h2 later
  u16* Qbf = (u16*)(ws + 0);
  u16* Kbf = Qbf + 8388608;
  float* rq = (float*)(ws + 32 * MB);
  float* rk = rq + 8192;
  u16* h2  = (u16*)(ws + 0);
  // region 1 [64,96MB): xbf[64,80) Vbf[80,96)  -> P[64,96) after transpose
  u16* xbf = (u16*)(ws + 64 * MB);
  u16* Vbf = xbf + (size_t)8192 * 1024;
  u16* P   = (u16*)(ws + 64 * MB);
  // region 2 [96,120MB): weights bf16
  u16* Wq_b = (u16*)(ws + 96 * MB);
  u16* Wk_b = Wq_b + 1048576;
  u16* Wv_b = Wk_b + 1048576;
  u16* W1_b = Wv_b + 1048576;
  u16* W2_b = W1_b + 1048576;
  u16* W3_b = W2_b + 4194304;
  // region 3 [120,168MB): attnout[120,136) h1[136,152) Vt[152,168)
  u16* attnout = (u16*)(ws + 120 * MB);
  u16* h1      = attnout + 8388608;
  u16* Vt      = h1 + 8388608;

  CastSegs cs;
  cs.src[0] = x;  cs.dst[0] = xbf;
  cs.src[1] = Wq; cs.dst[1] = Wq_b;
  cs.src[2] = Wk; cs.dst[2] = Wk_b;
  cs.src[3] = Wv; cs.dst[3] = Wv_b;
  cs.src[4] = W1; cs.dst[4] = W1_b;
  cs.src[5] = W2; cs.dst[5] = W2_b;
  cs.src[6] = W3; cs.dst[6] = W3_b;
  long szs[7] = {2097152, 262144, 262144, 262144, 262144, 1048576, 1048576};
  long acc0 = 0;
  for (int i = 0; i < 7; ++i) { cs.beg[i] = acc0; acc0 += szs[i]; }
  cs.beg[7] = acc0;
  cast_multi_kernel<<<dim3((unsigned)((acc0 + 255) / 256)), 256, 0, stream>>>(cs);

  // 2. fused QKV: M=8192, N=3072, K=1024 (256^2, grid 384, GBY=8)
  gemm256<2><<<dim3(12 * 32), 512, 0, stream>>>(
      xbf, Wq_b, bq, Qbf, bk, Kbf, bv, Vbf, 3072, 1024, 0, 0, 0, 0, 12, 32, 8);
  // 3. inverse norms (tiny out) + V transpose
  norms_kernel<<<16384, 256, 0, stream>>>(Qbf, Kbf, rq, rk);
  transpose_kernel<<<dim3(32, 64, 4), dim3(32, 8), 0, stream>>>(Vbf, Vt, 2048, 1024);
  // 4. sim = (Q@K^T)*rq[r]*rk[c] -> bf16 P-logits (256^2, grid 256, GBY=8)
  gemm256<3><<<dim3(8 * 8 * 4), 512, 0, stream>>>(
      Qbf, Kbf, rq, P, rk, nullptr, nullptr, nullptr,
      2048, 1024, 2097152L, 2097152L, 4194304L, 0, 8, 8, 8);
  // 5. softmax (bf16 in/out), in-place on P
  softmax_kernel<<<8192, 256, 0, stream>>>(P, P);
  // 6. attnout = P @ V (gemmra, grid 256, GBY=8)
  gemmra<1><<<dim3(4 * 16 * 4), 512, 0, stream>>>(
      P, Vt, nullptr, attnout, 1024, 2048, 4194304L, 2097152L, 2097152L, 0, 4, 16, 8);
  // 7. MLP
  gemmra<1><<<dim3(4 * 64), 512, 0, stream>>>(
      attnout, W1_b, b1, h1, 1024, 1024, 0, 0, 0, 1, 4, 64, 16);
  gemm256<1><<<dim3(16 * 32), 512, 0, stream>>>(
      h1, W2_b, b2, h2, nullptr, nullptr, nullptr, nullptr,
      4096, 1024, 0, 0, 0, 1, 16, 32, 8);
  gemmra<0><<<dim3(4 * 64), 512, 0, stream>>>(
      h2, W3_b, b3, (float*)d_out, 1024, 4096, 0, 0, 0, 0, 4, 64, 16);
}